// Round 2
// baseline (211.206 us; speedup 1.0000x reference)
//
#include <hip/hip_runtime.h>
#include <cstdint>

// Two-link planar arm forward dynamics: qdd = M(q)^-1 (tau - h(q,dq)).
// Purely elementwise per batch row -> HBM-bandwidth bound.
// fp32 in / fp32 out (per reference dtypes; round-1 NaN proved inputs are
// fp32 — reading them as bf16 produced Inf/NaN exponent patterns).
// Each thread processes 2 rows => 16B float4 loads/stores per operand.

__global__ __launch_bounds__(256) void fd_qdd_kernel(
    const float4* __restrict__ qp,
    const float4* __restrict__ dqp,
    const float4* __restrict__ taup,
    float4* __restrict__ outp,
    int nvec)  // number of float4 groups (= 2 rows each)
{
    int i = blockIdx.x * blockDim.x + threadIdx.x;
    if (i >= nvec) return;

    float4 qv = qp[i];
    float4 dv = dqp[i];
    float4 tv = taup[i];
    float4 ov;

    // Arm constants (L1=L2=1, C1=C2=0.5, M1=M2=1, I1=I2=0.1, G=9.81)
    const float alpha = 1.7f;     // I1 + M1*C1^2 + I2 + M2*(L1^2 + C2^2)
    const float beta  = 0.5f;     // M2*L1*C2
    const float delta = 0.35f;    // I2 + M2*C2^2  (== M22)
    const float G     = 9.81f;
    const float gA    = 1.5f * G; // (M1*C1 + M2*L1)*G
    const float gB    = 0.5f * G; // M2*C2*G

    const float* qs = (const float*)&qv;
    const float* ds = (const float*)&dv;
    const float* ts = (const float*)&tv;
    float*       os = (float*)&ov;

#pragma unroll
    for (int j = 0; j < 2; ++j) {
        float q1   = qs[2 * j + 0];
        float q2   = qs[2 * j + 1];
        float dq1  = ds[2 * j + 0];
        float dq2  = ds[2 * j + 1];
        float tau1 = ts[2 * j + 0];
        float tau2 = ts[2 * j + 1];

        float c2 = __cosf(q2);
        float s2 = __sinf(q2);

        float M11 = alpha + 2.0f * beta * c2;
        float M12 = delta + beta * c2;
        float M22 = delta;

        float cq1  = __cosf(q1);
        float cq12 = __cosf(q1 + q2);

        float g1 = gA * cq1 + gB * cq12;
        float g2 = gB * cq12;

        float h1 = -beta * s2 * (2.0f * dq1 * dq2 + dq2 * dq2) + g1;
        float h2 =  beta * s2 * dq1 * dq1 + g2;

        float r1 = tau1 - h1;
        float r2 = tau2 - h2;

        float det  = M11 * M22 - M12 * M12;
        float rdet = __frcp_rn(det);

        float qdd1 = (M22 * r1 - M12 * r2) * rdet;
        float qdd2 = (M11 * r2 - M12 * r1) * rdet;

        os[2 * j + 0] = qdd1;
        os[2 * j + 1] = qdd2;
    }

    outp[i] = ov;
}

extern "C" void kernel_launch(void* const* d_in, const int* in_sizes, int n_in,
                              void* d_out, int out_size, void* d_ws, size_t ws_size,
                              hipStream_t stream) {
    const float4* q   = (const float4*)d_in[0];
    const float4* dq  = (const float4*)d_in[1];
    const float4* tau = (const float4*)d_in[2];
    float4*       out = (float4*)d_out;

    int n_elems = in_sizes[0];      // B*2 fp32 elements
    int nvec    = n_elems / 4;      // 4 fp32 per float4 (2 rows)

    int block = 256;
    int grid  = (nvec + block - 1) / block;
    fd_qdd_kernel<<<grid, block, 0, stream>>>(q, dq, tau, out, nvec);
}